// Round 8
// baseline (130.617 us; speedup 1.0000x reference)
//
#include <hip/hip_runtime.h>

// CharGRU2: 2-layer GRU (reset_after=true) + dense + softmax, fp32.
// B=2048, T=128, V=256, H=20, L=15.
//
// Round 20: BARRIER-FREE LAYER-SPLIT PRODUCER/CONSUMER, R16 math.
//
//  Corrected HW model (R19): v_pk_fma_f32 is half-rate per element on CDNA4
//  (157 TF = 1 scalar fma/lane/cy), so R16's 58% VALUBusy is ~all real ALU
//  occupancy; each wave alone is issue-ready only ~29% of the time and two
//  identical waves stack to 58% (idle = 0.71^2). Four role-diverse waves
//  per SIMD should reach ~0.71^4 => ~75-80% busy — R18 proved 4 waves/SIMD
//  is reachable but its 129 block-wide __syncthreads re-lockstepped the
//  waves. This round removes ALL barriers:
//   - h0 ring is FULL-LENGTH (128 slots x 24 floats = 12KB/batch, 49.6KB/
//     block, 2 blocks/CU = 99KB < 160KB LDS): producer never wraps, never
//     waits, publishes h0_t then bumps a per-batch LDS counter (DS ops are
//     per-wave in-order => data lands before counter).
//   - consumer spin-polls the counter (volatile LDS read); producer has
//     less work/step so polls ~always succeed first try; producer EXITS
//     after t=127, freeing issue slots for consumer tails.
//   - consumer prefetches h0_{t+1} quads BEFORE its gate block so the
//     ds_read latency hides under the trans chains.
//
//  Failed-experiment ledger (do not retry): R13 s_sleep stagger (null),
//  R14/15 readlane->SGPR dots (-29%), R17 1 wave/SIMD 2-batch ILP (-24%),
//  R18 barrier-synced producer/consumer (-31%), R19 asm pk_fma + unroll4
//  (-17%: pk is half-rate per element; asm hampered scheduling).
//
// Layout recap: lane 16r+3u+p owns gate column p*20+(5r+u) (p=0:z 1:r 2:h~);
// home lane of unit j = 16*(j/5)+3*(j%5)+2; lane 16r+15 dups pos 14 and is
// excluded from LDS writes. Gate hops never cross a 16-lane DPP row.

#define BB 2048
#define TT 128
#define HH 20
#define LL 15
#define H3 60

typedef float v2f __attribute__((ext_vector_type(2)));

#if __has_builtin(__builtin_amdgcn_exp2f)
#define EXP2(x) __builtin_amdgcn_exp2f(x)
#else
#define EXP2(x) exp2f(x)
#endif

__device__ __forceinline__ float bclane(float v, int k) {
    return __int_as_float(__builtin_amdgcn_readlane(__float_as_int(v), k));
}
__device__ __forceinline__ float dpp_rshr1(float v) {
    return __int_as_float(__builtin_amdgcn_update_dpp(
        0, __float_as_int(v), 0x111, 0xF, 0xF, true));
}
__device__ __forceinline__ float dpp_rshr2(float v) {
    return __int_as_float(__builtin_amdgcn_update_dpp(
        0, __float_as_int(v), 0x112, 0xF, 0xF, true));
}
__device__ __forceinline__ float fast_rcp(float x) { return __builtin_amdgcn_rcpf(x); }
#define PIN(v) asm volatile("" : "+v"(v))
#define LDSFENCE() asm volatile("" ::: "memory")

// gate block: one exp2/rcp stream serves z,r (sigmoid) and h~ (tanh) lanes
#define GATES(XW, REC, H)                                                     \
    {                                                                         \
        const float e_  = EXP2((XW) + (REC));                                 \
        const float t_  = fast_rcp(1.f + e_);                                 \
        const float rv_ = dpp_rshr1(t_);                                      \
        const float zv_ = dpp_rshr2(t_);                                      \
        const float eh_ = EXP2(fmaf(rv_, (REC), (XW)));                       \
        const float th_ = fast_rcp(1.f + eh_);                                \
        const float hh_ = fmaf(2.f, th_, -1.f);                               \
        H = fmaf(zv_, (H) - hh_, hh_);                                        \
    }
// dot: C (5 float4 quads) . P (10 v2f cols) + bias (v2f{b,0}) -> scalar OUT
#define DOTD(C, P, BIASV, OUT)                                                \
    {                                                                         \
        v2f aa = BIASV, ab = v2f{0.f, 0.f};                                   \
        _Pragma("unroll")                                                     \
        for (int q = 0; q < 5; ++q) {                                         \
            aa = __builtin_elementwise_fma(v2f{C[q].x, C[q].y}, P[2 * q], aa);\
            ab = __builtin_elementwise_fma(v2f{C[q].z, C[q].w}, P[2 * q + 1], ab);\
        }                                                                     \
        const v2f t_ = aa + ab;                                               \
        OUT = t_.x + t_.y;                                                    \
    }

extern "C" __global__ __launch_bounds__(512, 4)
void gru2_kernel(const int* __restrict__ x, const float* __restrict__ W0,
                 const float* __restrict__ U0, const float* __restrict__ b0i,
                 const float* __restrict__ b0r, const float* __restrict__ W1,
                 const float* __restrict__ U1, const float* __restrict__ b1i,
                 const float* __restrict__ b1r, const float* __restrict__ Wd,
                 const float* __restrict__ bd, float* __restrict__ out)
{
    const int lane = threadIdx.x & 63;
    const int w    = threadIdx.x >> 6;                   // 0..7
    const int g    = w & 3;                              // batch group
    const int role = w >> 2;                             // 0: L0 prod, 1: L1 cons
    const int batch = blockIdx.x * 4 + g;

    const int row = lane >> 4;
    const int pos = lane & 15;
    const int pc  = (pos < 15) ? pos : 14;
    const int u   = pc / 3;
    const int p3  = pc % 3;                              // 0:z 1:r 2:h~
    const int j   = row * 5 + u;
    const bool home = (pos < 15) && (p3 == 2);
    const int col = p3 * 20 + j;

    // exp2 gate scale: z/r columns -log2e, h~ columns -2log2e
    const float gsc = (p3 == 2) ? -2.8853900817779268f : -1.4426950408889634f;

    // full-length h0 ring (never wraps) + consumer h1 buf + flags
    __shared__ __align__(16) float ring[4][TT][24];      // 49152 B
    __shared__ __align__(16) float h1s[4][24];
    __shared__ int cnts[4];
    float* myring = &ring[g][0][0];
    float* h1buf  = &h1s[g][0];
    volatile int* vcnt = &cnts[g];

    if (threadIdx.x < 4) cnts[threadIdx.x] = 0;
    __syncthreads();                                     // once, at start only

    if (role == 0) {
        // ================= PRODUCER: layer 0 =================
        v2f u0p[10];
#pragma unroll
        for (int q = 0; q < 10; ++q) {
            const int k0 = (2 * q) * H3, k1 = (2 * q + 1) * H3;
            u0p[q] = v2f{U0[k0 + col] * gsc, U0[k1 + col] * gsc};
        }
#pragma unroll
        for (int q = 0; q < 10; ++q) PIN(u0p[q]);
        const float bi0 = b0i[col] * gsc, br0 = b0r[col] * gsc;
        const v2f br0v = v2f{br0, 0.f};

        const int* xrow = x + batch * TT;
        const int tokA = xrow[lane];
        const int tokB = xrow[64 + lane];
        int tokn2 = __builtin_amdgcn_readlane(tokA, 2);
        float xw_cur = fmaf(W0[__builtin_amdgcn_readlane(tokA, 0) * H3 + col], gsc, bi0);
        float xw_nxt = W0[__builtin_amdgcn_readlane(tokA, 1) * H3 + col];

        float h0 = 0.f;
        float rec0 = br0;                                // h0_{-1} = 0
        float4 c0[5];

#pragma unroll 2
        for (int t = 0; t < TT; ++t) {
            const int t3 = (t + 3 < TT) ? (t + 3) : (TT - 1);
            const float pf = W0[tokn2 * H3 + col];
            const int tokn3 =
                __builtin_amdgcn_readlane(t3 < 64 ? tokA : tokB, t3 & 63);

            GATES(xw_cur, rec0, h0);                     // -> h0_t
            float* slot = myring + t * 24;
            if (home) slot[j] = h0;
            LDSFENCE();
            if (lane == 63) *vcnt = t + 1;               // publish (DS in-order)
            const float4* sq = (const float4*)slot;
#pragma unroll
            for (int q = 0; q < 5; ++q) c0[q] = sq[q];   // own quads for t+1

            xw_cur = fmaf(xw_nxt, gsc, bi0);             // rotate W0 pipeline
            xw_nxt = pf; tokn2 = tokn3;

            DOTD(c0, u0p, br0v, rec0);                   // tail dot for t+1
        }
        return;                                          // free the SIMD slot
    }

    // ================= CONSUMER: layer 1 + dense =================
    v2f w1p[10], u1p[10];
#pragma unroll
    for (int q = 0; q < 10; ++q) {
        const int k0 = (2 * q) * H3, k1 = (2 * q + 1) * H3;
        w1p[q] = v2f{W1[k0 + col] * gsc, W1[k1 + col] * gsc};
        u1p[q] = v2f{U1[k0 + col] * gsc, U1[k1 + col] * gsc};
    }
#pragma unroll
    for (int q = 0; q < 10; ++q) { PIN(w1p[q]); PIN(u1p[q]); }
    const float bi1 = b1i[col] * gsc, br1 = b1r[col] * gsc;
    const v2f bi1v = v2f{bi1, 0.f}, br1v = v2f{br1, 0.f};

    float h1 = 0.f;
    float4 c0[5], c1[5];
    float xw1, rec1;

    // prologue: wait for h0_0, build first dots
    while (*vcnt < 1) {}
    {
        const float4* sq = (const float4*)myring;
#pragma unroll
        for (int q = 0; q < 5; ++q) c0[q] = sq[q];
        DOTD(c0, w1p, bi1v, xw1);                        // h0_0 . W1 + bi1
        rec1 = br1;                                      // h1_{-1} = 0
    }

#pragma unroll 2
    for (int t = 0; t < TT; ++t) {
        // prefetch h0_{t+1} quads: poll, then reads hide under GATES
        if (t < TT - 1) {
            while (*vcnt < t + 2) {}
            const float4* sq = (const float4*)(myring + (t + 1) * 24);
#pragma unroll
            for (int q = 0; q < 5; ++q) c0[q] = sq[q];
        }

        GATES(xw1, rec1, h1);                            // -> h1_t
        if (home) h1buf[j] = h1;
        LDSFENCE();
        const float4* q1 = (const float4*)h1buf;
#pragma unroll
        for (int q = 0; q < 5; ++q) c1[q] = q1[q];       // h1_t quads

        if (t < TT - 1) {
            DOTD(c0, w1p, bi1v, xw1);                    // h0_{t+1} . W1 + bi1
            DOTD(c1, u1p, br1v, rec1);                   // h1_t    . U1 + br1
        }
    }

    // ---- dense (h1 @ Wd + bd) + softmax, lanes 0..14 ----
    const int l = lane < LL ? lane : LL - 1;
    float acc = bd[l];
#pragma unroll
    for (int k = 0; k < HH; ++k)
        acc = fmaf(h1buf[k], Wd[k * LL + l], acc);       // LDS broadcast reads

    float m = acc;
#pragma unroll
    for (int i = 0; i < LL; ++i) m = fmaxf(m, bclane(acc, i));
    const float e = __expf(acc - m);
    float s = 0.f;
#pragma unroll
    for (int i = 0; i < LL; ++i) s += bclane(e, i);
    const float pr = e * fast_rcp(s);

    if (lane < LL) out[batch * LL + lane] = pr;
}

extern "C" void kernel_launch(void* const* d_in, const int* in_sizes, int n_in,
                              void* d_out, int out_size, void* d_ws, size_t ws_size,
                              hipStream_t stream) {
    const int*   x   = (const int*)  d_in[0];
    const float* W0  = (const float*)d_in[1];
    const float* U0  = (const float*)d_in[2];
    const float* b0i = (const float*)d_in[3];
    const float* b0r = (const float*)d_in[4];
    const float* W1  = (const float*)d_in[5];
    const float* U1  = (const float*)d_in[6];
    const float* b1i = (const float*)d_in[7];
    const float* b1r = (const float*)d_in[8];
    const float* Wd  = (const float*)d_in[9];
    const float* bd  = (const float*)d_in[10];
    // d_in[11] = drop_rate (identity), unused
    float* out = (float*)d_out;

    // 2 waves/batch (L0 prod | L1 cons), 4 batches/block (512 thr) ->
    // 512 blocks = 2 blocks/CU = 4 waves/SIMD (2 prod + 2 cons), no barriers.
    dim3 grid(BB / 4), block(512);
    hipLaunchKernelGGL(gru2_kernel, grid, block, 0, stream,
                       x, W0, U0, b0i, b0r, W1, U1, b1i, b1r, Wd, bd, out);
}